// Round 5
// baseline (620.440 us; speedup 1.0000x reference)
//
#include <hip/hip_runtime.h>
#include <hip/hip_bf16.h>
#include <hip/hip_fp16.h>

#define N_PTS 500000
#define P_POLY 50000
#define IN_DIM 9
#define HDIM 128
#define EPSV 1e-5f
#define BUCKET_CAP 64
#define TILES64 7813         // ceil(500000 / 64)
#define ENC_BLOCKS 512       // 2 blocks/CU

typedef __attribute__((ext_vector_type(8))) short short8;
typedef __attribute__((ext_vector_type(4))) float floatx4;

__device__ __forceinline__ unsigned short f2h(float f) {
  return __half_as_ushort(__float2half(f));
}
__device__ __forceinline__ float h2f(unsigned short u) {
  return __half2float(__ushort_as_half(u));
}

// ---------------- bucket build: per-polyline row lists (no scan) ----------------
__global__ __launch_bounds__(256) void k_bucket(
    const int* __restrict__ ids, unsigned int* __restrict__ cnt, int* __restrict__ list)
{
  int i = blockIdx.x * blockDim.x + threadIdx.x;
  if (i < N_PTS) {
    int id = ids[i];
    unsigned k = atomicAdd(&cnt[id], 1u);
    list[id * BUCKET_CAP + (k & (BUCKET_CAP - 1))] = i;
  }
}

// ---------------- W prep: W[256][128] fp32 -> Wsw = W^T [128][256] f16 ----------------
__global__ __launch_bounds__(256) void k_wprep(
    const float* __restrict__ Wa, const float* __restrict__ Wb,
    unsigned short* __restrict__ Oa, unsigned short* __restrict__ Ob)
{
  int which = blockIdx.x >> 3;
  int part = blockIdx.x & 7;
  const float* W = which ? Wb : Wa;
  unsigned short* O = which ? Ob : Oa;
  for (int i = threadIdx.x; i < 4096; i += 256) {
    int idx = part * 4096 + i;
    int c = idx & 127;
    int k = idx >> 7;
    O[c * 256 + k] = f2h(W[k * 128 + c]);
  }
}

// ---------------- K1: encoder0 (fp32 VALU), h only ----------------
__global__ __launch_bounds__(256) void k_enc0(
    const float* __restrict__ x,
    const float* __restrict__ W0, const float* __restrict__ b0,
    const float* __restrict__ g0, const float* __restrict__ be0,
    unsigned short* __restrict__ h)
{
  __shared__ float sW[IN_DIM * HDIM];
  __shared__ float sb[HDIM], sg[HDIM], sbe[HDIM];
  for (int t = threadIdx.x; t < IN_DIM * HDIM; t += 256) sW[t] = W0[t];
  if (threadIdx.x < HDIM) {
    sb[threadIdx.x] = b0[threadIdx.x];
    sg[threadIdx.x] = g0[threadIdx.x];
    sbe[threadIdx.x] = be0[threadIdx.x];
  }
  __syncthreads();
  const int lane = threadIdx.x & 63;
  const int c0 = lane * 2;
  const float bc0 = sb[c0], bc1 = sb[c0 + 1];
  const float gc0 = sg[c0], gc1 = sg[c0 + 1];
  const float bec0 = sbe[c0], bec1 = sbe[c0 + 1];
  int wid = blockIdx.x * 4 + (threadIdx.x >> 6);
  const int nw = gridDim.x * 4;
  for (int row = wid; row < N_PTS; row += nw) {
    const float* xr = x + (size_t)row * IN_DIM;
    float z0 = bc0, z1 = bc1;
#pragma unroll
    for (int k = 0; k < IN_DIM; ++k) {
      float xv = xr[k];
      z0 = fmaf(xv, sW[k * HDIM + c0], z0);
      z1 = fmaf(xv, sW[k * HDIM + c0 + 1], z1);
    }
    float s = z0 + z1, ss = fmaf(z0, z0, z1 * z1);
#pragma unroll
    for (int m = 32; m >= 1; m >>= 1) {
      s += __shfl_xor(s, m);
      ss += __shfl_xor(ss, m);
    }
    float mu = s * (1.0f / 128.0f);
    float var = ss * (1.0f / 128.0f) - mu * mu;
    float rs = rsqrtf(var + EPSV);
    float v0 = fmaxf(fmaf((z0 - mu) * rs, gc0, bec0), 0.0f);
    float v1 = fmaxf(fmaf((z1 - mu) * rs, gc1, bec1), 0.0f);
    ushort2 hp;
    hp.x = f2h(v0);
    hp.y = f2h(v1);
    *reinterpret_cast<ushort2*>(h + (size_t)row * HDIM + c0) = hp;
  }
}

// ---------------- segmax: one wave per polyline; batch-issued gather ----------------
template <int MODE>
__global__ __launch_bounds__(256) void k_segmax(
    const unsigned short* __restrict__ h, const unsigned int* __restrict__ cnt,
    const int* __restrict__ list, unsigned short* __restrict__ aggh,
    float* __restrict__ out)
{
  int p = blockIdx.x * 4 + (threadIdx.x >> 6);
  const int lane = threadIdx.x & 63;
  int n = (int)cnt[p];
  if (n > BUCKET_CAP) n = BUCKET_CAP;
  int myidx = list[p * BUCKET_CAP + lane];
  float m0 = 0.f, m1 = 0.f;  // empty segments -> 0 per reference semantics
  for (int k = 0; k < n; k += 8) {
    int kn = n - k;
    int r[8];
    ushort2 v[8];
#pragma unroll
    for (int j = 0; j < 8; ++j) r[j] = __shfl(myidx, k + j);
#pragma unroll
    for (int j = 0; j < 8; ++j)
      if (j < kn) v[j] = *reinterpret_cast<const ushort2*>(h + (size_t)r[j] * 128 + lane * 2);
#pragma unroll
    for (int j = 0; j < 8; ++j)
      if (j < kn) {
        m0 = fmaxf(m0, h2f(v[j].x));
        m1 = fmaxf(m1, h2f(v[j].y));
      }
  }
  if (MODE == 0) {
    ushort2 r;
    r.x = f2h(m0);
    r.y = f2h(m1);
    *reinterpret_cast<ushort2*>(aggh + (size_t)p * 128 + lane * 2) = r;
  } else {
    float2 r;
    r.x = m0;
    r.y = m1;
    *reinterpret_cast<float2*>(out + (size_t)p * 128 + lane * 2) = r;
    if (lane == 0) out[(size_t)P_POLY * 128 + p] = (float)p;
  }
}

// ------------- K2/K3: MFMA encoder, W register-resident (256-VGPR budget) -------------
// Block = 4 waves; wave w owns output cols [w*32, w*32+32). B-frags = 64 VGPRs, loaded
// once. Per 64-row tile: 32 A-loads, 64 MFMAs, two-stage cross-wave LN (2 barriers),
// direct f16 stores. launch_bounds(256,2) -> VGPR cap 256 so B stays resident.
__global__ __launch_bounds__(256, 2) void k_enc(
    const unsigned short* __restrict__ hin,   // [N,128] f16
    const unsigned short* __restrict__ aggbf, // [P,128] f16
    const int* __restrict__ ids,
    const unsigned short* __restrict__ Wsw,   // [128 cols][256 k] f16 (W^T)
    const float* __restrict__ bias, const float* __restrict__ gamma,
    const float* __restrict__ beta,
    unsigned short* __restrict__ hout)        // aliases hin (tile-local rows only)
{
  __shared__ float2 part[4][64];   // [wave][row-in-tile] (sum, sumsq)
  __shared__ float2 mufin[64];     // [row-in-tile] (mu, rs)

  const int lane = threadIdx.x & 63;
  const int w = threadIdx.x >> 6;
  const int l15 = lane & 15;
  const int l4 = lane >> 4;
  const int koff = l4 * 8;

  const int c0 = w * 32 + l15;
  const int c1 = c0 + 16;
  const float bi0 = bias[c0], bi1 = bias[c1];
  const float ga0 = gamma[c0], ga1 = gamma[c1];
  const float bt0 = beta[c0], bt1 = beta[c1];

  short8 B0[8], B1[8];  // 64 VGPRs, loaded once per persistent block
#pragma unroll
  for (int kt = 0; kt < 8; ++kt) {
    B0[kt] = *reinterpret_cast<const short8*>(Wsw + c0 * 256 + kt * 32 + koff);
    B1[kt] = *reinterpret_cast<const short8*>(Wsw + c1 * 256 + kt * 32 + koff);
  }

  for (int t = blockIdx.x; t < TILES64; t += gridDim.x) {
    const int rowBase = t * 64;

    const unsigned short* hp0;
    const unsigned short* hp1;
    const unsigned short* hp2;
    const unsigned short* hp3;
    const unsigned short* gp0;
    const unsigned short* gp1;
    const unsigned short* gp2;
    const unsigned short* gp3;
    {
      int r0 = rowBase + 0 * 16 + l15;  r0 = r0 < N_PTS ? r0 : N_PTS - 1;
      int r1 = rowBase + 1 * 16 + l15;  r1 = r1 < N_PTS ? r1 : N_PTS - 1;
      int r2 = rowBase + 2 * 16 + l15;  r2 = r2 < N_PTS ? r2 : N_PTS - 1;
      int r3 = rowBase + 3 * 16 + l15;  r3 = r3 < N_PTS ? r3 : N_PTS - 1;
      hp0 = hin + (size_t)r0 * 128;  gp0 = aggbf + (size_t)ids[r0] * 128;
      hp1 = hin + (size_t)r1 * 128;  gp1 = aggbf + (size_t)ids[r1] * 128;
      hp2 = hin + (size_t)r2 * 128;  gp2 = aggbf + (size_t)ids[r2] * 128;
      hp3 = hin + (size_t)r3 * 128;  gp3 = aggbf + (size_t)ids[r3] * 128;
    }

    floatx4 acc0c0 = {0.f,0.f,0.f,0.f}, acc0c1 = {0.f,0.f,0.f,0.f};
    floatx4 acc1c0 = {0.f,0.f,0.f,0.f}, acc1c1 = {0.f,0.f,0.f,0.f};
    floatx4 acc2c0 = {0.f,0.f,0.f,0.f}, acc2c1 = {0.f,0.f,0.f,0.f};
    floatx4 acc3c0 = {0.f,0.f,0.f,0.f}, acc3c1 = {0.f,0.f,0.f,0.f};

#pragma unroll
    for (int kt = 0; kt < 8; ++kt) {
      const int off = (kt & 3) * 32 + koff;
      short8 a0 = *reinterpret_cast<const short8*>((kt < 4 ? hp0 : gp0) + off);
      short8 a1 = *reinterpret_cast<const short8*>((kt < 4 ? hp1 : gp1) + off);
      short8 a2 = *reinterpret_cast<const short8*>((kt < 4 ? hp2 : gp2) + off);
      short8 a3 = *reinterpret_cast<const short8*>((kt < 4 ? hp3 : gp3) + off);
      acc0c0 = __builtin_amdgcn_mfma_f32_16x16x32_f16(a0, B0[kt], acc0c0, 0, 0, 0);
      acc0c1 = __builtin_amdgcn_mfma_f32_16x16x32_f16(a0, B1[kt], acc0c1, 0, 0, 0);
      acc1c0 = __builtin_amdgcn_mfma_f32_16x16x32_f16(a1, B0[kt], acc1c0, 0, 0, 0);
      acc1c1 = __builtin_amdgcn_mfma_f32_16x16x32_f16(a1, B1[kt], acc1c1, 0, 0, 0);
      acc2c0 = __builtin_amdgcn_mfma_f32_16x16x32_f16(a2, B0[kt], acc2c0, 0, 0, 0);
      acc2c1 = __builtin_amdgcn_mfma_f32_16x16x32_f16(a2, B1[kt], acc2c1, 0, 0, 0);
      acc3c0 = __builtin_amdgcn_mfma_f32_16x16x32_f16(a3, B0[kt], acc3c0, 0, 0, 0);
      acc3c1 = __builtin_amdgcn_mfma_f32_16x16x32_f16(a3, B1[kt], acc3c1, 0, 0, 0);
    }

    // bias + per-lane partial (sum over this wave's 2 cols), 16-lane tree, LDS write
#pragma unroll
    for (int rg = 0; rg < 4; ++rg) {
      floatx4* aC0 = rg == 0 ? &acc0c0 : rg == 1 ? &acc1c0 : rg == 2 ? &acc2c0 : &acc3c0;
      floatx4* aC1 = rg == 0 ? &acc0c1 : rg == 1 ? &acc1c1 : rg == 2 ? &acc2c1 : &acc3c1;
      float s[4], ss[4];
#pragma unroll
      for (int r = 0; r < 4; ++r) {
        float z0 = (*aC0)[r] + bi0;
        float z1 = (*aC1)[r] + bi1;
        (*aC0)[r] = z0;
        (*aC1)[r] = z1;
        s[r] = z0 + z1;
        ss[r] = fmaf(z0, z0, z1 * z1);
      }
#pragma unroll
      for (int m = 1; m <= 8; m <<= 1) {
#pragma unroll
        for (int r = 0; r < 4; ++r) {
          s[r] += __shfl_xor(s[r], m);
          ss[r] += __shfl_xor(ss[r], m);
        }
      }
      if (l15 == 0) {
#pragma unroll
        for (int r = 0; r < 4; ++r)
          part[w][rg * 16 + l4 * 4 + r] = make_float2(s[r], ss[r]);
      }
    }
    __syncthreads();

    // stage 2: threads 0..63 finalize one row each
    if (threadIdx.x < 64) {
      int rr = threadIdx.x;
      float2 qa = part[0][rr], qb = part[1][rr], qc = part[2][rr], qd = part[3][rr];
      float S = qa.x + qb.x + qc.x + qd.x;
      float SS = qa.y + qb.y + qc.y + qd.y;
      float mu = S * (1.f / 128.f);
      float rs = rsqrtf(SS * (1.f / 128.f) - mu * mu + EPSV);
      mufin[rr] = make_float2(mu, rs);
    }
    __syncthreads();

    // epilogue: normalize + affine + relu -> f16 -> global stores (guarded tail)
#pragma unroll
    for (int rg = 0; rg < 4; ++rg) {
      const floatx4* aC0 = rg == 0 ? &acc0c0 : rg == 1 ? &acc1c0 : rg == 2 ? &acc2c0 : &acc3c0;
      const floatx4* aC1 = rg == 0 ? &acc0c1 : rg == 1 ? &acc1c1 : rg == 2 ? &acc2c1 : &acc3c1;
#pragma unroll
      for (int r = 0; r < 4; ++r) {
        int rloc = rg * 16 + l4 * 4 + r;
        int row = rowBase + rloc;
        float2 q = mufin[rloc];
        float v0 = fmaxf(fmaf(((*aC0)[r] - q.x) * q.y, ga0, bt0), 0.f);
        float v1 = fmaxf(fmaf(((*aC1)[r] - q.x) * q.y, ga1, bt1), 0.f);
        if (row < N_PTS) {
          hout[(size_t)row * 128 + c0] = f2h(v0);
          hout[(size_t)row * 128 + c1] = f2h(v1);
        }
      }
    }
  }
}

// ws layout (bytes)
#define WS_H 0
#define WS_AGG 128000000
#define WS_CNT 140800000
#define WS_LIST 141004800
#define WS_W1 153804800
#define WS_W2 153870336
#define WS_NEED 153935872

__device__ __attribute__((aligned(256))) unsigned char g_fallback[WS_NEED];

extern "C" void kernel_launch(void* const* d_in, const int* in_sizes, int n_in,
                              void* d_out, int out_size, void* d_ws, size_t ws_size,
                              hipStream_t stream) {
  const float* x = (const float*)d_in[0];
  const int* ids = (const int*)d_in[1];
  const float* W0 = (const float*)d_in[2];
  const float* b0 = (const float*)d_in[3];
  const float* g0 = (const float*)d_in[4];
  const float* be0 = (const float*)d_in[5];
  const float* W1 = (const float*)d_in[6];
  const float* b1 = (const float*)d_in[7];
  const float* g1 = (const float*)d_in[8];
  const float* be1 = (const float*)d_in[9];
  const float* W2 = (const float*)d_in[10];
  const float* b2 = (const float*)d_in[11];
  const float* g2 = (const float*)d_in[12];
  const float* be2 = (const float*)d_in[13];

  char* ws = (char*)d_ws;
  if (ws_size < (size_t)WS_NEED) {
    void* p = nullptr;
    hipGetSymbolAddress(&p, HIP_SYMBOL(g_fallback));
    ws = (char*)p;
  }
  unsigned short* h = (unsigned short*)(ws + WS_H);
  unsigned short* aggh = (unsigned short*)(ws + WS_AGG);
  unsigned int* cnt = (unsigned int*)(ws + WS_CNT);
  int* list = (int*)(ws + WS_LIST);
  unsigned short* Wsw1 = (unsigned short*)(ws + WS_W1);
  unsigned short* Wsw2 = (unsigned short*)(ws + WS_W2);
  float* out = (float*)d_out;

  hipMemsetAsync(cnt, 0, P_POLY * 4, stream);
  k_bucket<<<(N_PTS + 255) / 256, 256, 0, stream>>>(ids, cnt, list);
  k_wprep<<<16, 256, 0, stream>>>(W1, W2, Wsw1, Wsw2);
  k_enc0<<<4096, 256, 0, stream>>>(x, W0, b0, g0, be0, h);
  k_segmax<0><<<P_POLY / 4, 256, 0, stream>>>(h, cnt, list, aggh, nullptr);
  k_enc<<<ENC_BLOCKS, 256, 0, stream>>>(h, aggh, ids, Wsw1, b1, g1, be1, h);
  k_segmax<0><<<P_POLY / 4, 256, 0, stream>>>(h, cnt, list, aggh, nullptr);
  k_enc<<<ENC_BLOCKS, 256, 0, stream>>>(h, aggh, ids, Wsw2, b2, g2, be2, h);
  k_segmax<1><<<P_POLY / 4, 256, 0, stream>>>(h, cnt, list, nullptr, out);
}

// Round 6
// 597.884 us; speedup vs baseline: 1.0377x; 1.0377x over previous
//
#include <hip/hip_runtime.h>
#include <hip/hip_bf16.h>
#include <hip/hip_fp16.h>

#define N_PTS 500000
#define P_POLY 50000
#define IN_DIM 9
#define HDIM 128
#define EPSV 1e-5f
#define BUCKET_CAP 64

typedef __attribute__((ext_vector_type(8))) short short8;
typedef __attribute__((ext_vector_type(4))) float floatx4;

__device__ __forceinline__ unsigned short f2h(float f) {
  return __half_as_ushort(__float2half(f));
}
__device__ __forceinline__ float h2f(unsigned short u) {
  return __half2float(__ushort_as_half(u));
}

// ---------------- bucket build ----------------
__global__ __launch_bounds__(256) void k_bucket(
    const int* __restrict__ ids, unsigned int* __restrict__ cnt, int* __restrict__ list)
{
  int i = blockIdx.x * blockDim.x + threadIdx.x;
  if (i < N_PTS) {
    int id = ids[i];
    unsigned k = atomicAdd(&cnt[id], 1u);
    list[id * BUCKET_CAP + (k & (BUCKET_CAP - 1))] = i;
  }
}

// ---------------- scan stage 1: per-block totals ----------------
__global__ __launch_bounds__(256) void k_scan1(
    const unsigned int* __restrict__ cnt, unsigned int* __restrict__ btot)
{
  __shared__ unsigned int s[256];
  int t = threadIdx.x;
  int i = blockIdx.x * 256 + t;
  s[t] = (i < P_POLY) ? cnt[i] : 0u;
  __syncthreads();
  for (int d = 128; d > 0; d >>= 1) {
    if (t < d) s[t] += s[t + d];
    __syncthreads();
  }
  if (t == 0) btot[blockIdx.x] = s[0];
}

// ---------------- scan stage 2: offsets + fill pid_perm / ipos ----------------
__global__ __launch_bounds__(256) void k_scan2(
    const unsigned int* __restrict__ cnt, const unsigned int* __restrict__ btot,
    const int* __restrict__ list, unsigned int* __restrict__ offsets,
    int* __restrict__ pid_perm, int* __restrict__ ipos)
{
  __shared__ unsigned int s[256];
  __shared__ unsigned int sbase;
  int b = blockIdx.x, t = threadIdx.x;
  int i = b * 256 + t;
  unsigned int v = (i < P_POLY) ? cnt[i] : 0u;
  s[t] = v;
  __syncthreads();
  for (int d = 1; d < 256; d <<= 1) {
    unsigned int tmp = (t >= d) ? s[t - d] : 0u;
    __syncthreads();
    s[t] += tmp;
    __syncthreads();
  }
  unsigned int incl = s[t];
  if (t == 0) {
    unsigned int base = 0;
    for (int j = 0; j < b; ++j) base += btot[j];
    sbase = base;
  }
  __syncthreads();
  unsigned int off = sbase + incl - v;  // exclusive prefix
  if (i < P_POLY) {
    offsets[i] = off;
    unsigned int n = v > BUCKET_CAP ? (unsigned)BUCKET_CAP : v;
    for (unsigned int k = 0; k < n; ++k) {
      int r = list[i * BUCKET_CAP + k];
      pid_perm[off + k] = i;
      ipos[r] = (int)(off + k);
    }
  }
}

// ---------------- W prep: split + transpose to f16 [col][k] ----------------
// sel 0: Wt1 (W1 top k<128), 1: Wb1 (W1 bot), 2: Wt2, 3: Wb2
__global__ __launch_bounds__(256) void k_wprep(
    const float* __restrict__ W1, const float* __restrict__ W2,
    unsigned short* __restrict__ Wt1, unsigned short* __restrict__ Wb1,
    unsigned short* __restrict__ Wt2, unsigned short* __restrict__ Wb2)
{
  int idx = blockIdx.x * 256 + threadIdx.x;  // grid 256 -> 65536 total
  int sel = idx >> 14;
  int e = idx & 16383;
  int c = e & 127;
  int k = e >> 7;
  const float* W = (sel < 2) ? W1 : W2;
  unsigned short* O = sel == 0 ? Wt1 : sel == 1 ? Wb1 : sel == 2 ? Wt2 : Wb2;
  int kg = k + ((sel & 1) ? 128 : 0);
  O[c * 128 + k] = f2h(W[kg * 128 + c]);
}

// ---------------- K1: encoder0 (fp32 VALU) -> h in SORTED order ----------------
__global__ __launch_bounds__(256) void k_enc0(
    const float* __restrict__ x, const int* __restrict__ ipos,
    const float* __restrict__ W0, const float* __restrict__ b0,
    const float* __restrict__ g0, const float* __restrict__ be0,
    unsigned short* __restrict__ h)
{
  __shared__ float sW[IN_DIM * HDIM];
  __shared__ float sb[HDIM], sg[HDIM], sbe[HDIM];
  for (int t = threadIdx.x; t < IN_DIM * HDIM; t += 256) sW[t] = W0[t];
  if (threadIdx.x < HDIM) {
    sb[threadIdx.x] = b0[threadIdx.x];
    sg[threadIdx.x] = g0[threadIdx.x];
    sbe[threadIdx.x] = be0[threadIdx.x];
  }
  __syncthreads();
  const int lane = threadIdx.x & 63;
  const int c0 = lane * 2;
  const float bc0 = sb[c0], bc1 = sb[c0 + 1];
  const float gc0 = sg[c0], gc1 = sg[c0 + 1];
  const float bec0 = sbe[c0], bec1 = sbe[c0 + 1];
  int wid = blockIdx.x * 4 + (threadIdx.x >> 6);
  const int nw = gridDim.x * 4;
  for (int row = wid; row < N_PTS; row += nw) {
    const float* xr = x + (size_t)row * IN_DIM;
    float z0 = bc0, z1 = bc1;
#pragma unroll
    for (int k = 0; k < IN_DIM; ++k) {
      float xv = xr[k];
      z0 = fmaf(xv, sW[k * HDIM + c0], z0);
      z1 = fmaf(xv, sW[k * HDIM + c0 + 1], z1);
    }
    float s = z0 + z1, ss = fmaf(z0, z0, z1 * z1);
#pragma unroll
    for (int m = 32; m >= 1; m >>= 1) {
      s += __shfl_xor(s, m);
      ss += __shfl_xor(ss, m);
    }
    float mu = s * (1.0f / 128.0f);
    float var = ss * (1.0f / 128.0f) - mu * mu;
    float rs = rsqrtf(var + EPSV);
    float v0 = fmaxf(fmaf((z0 - mu) * rs, gc0, bec0), 0.0f);
    float v1 = fmaxf(fmaf((z1 - mu) * rs, gc1, bec1), 0.0f);
    ushort2 hp;
    hp.x = f2h(v0);
    hp.y = f2h(v1);
    int pos = ipos[row];
    *reinterpret_cast<ushort2*>(h + (size_t)pos * HDIM + c0) = hp;
  }
}

// ---------------- segmax: contiguous rows per polyline, streaming ----------------
template <int MODE>
__global__ __launch_bounds__(256) void k_segmax(
    const unsigned short* __restrict__ hp, const unsigned int* __restrict__ cnt,
    const unsigned int* __restrict__ offsets, unsigned short* __restrict__ aggh,
    float* __restrict__ out)
{
  int p = blockIdx.x * 4 + (threadIdx.x >> 6);
  const int lane = threadIdx.x & 63;
  int n = (int)cnt[p];
  if (n > BUCKET_CAP) n = BUCKET_CAP;
  const unsigned short* base = hp + (size_t)offsets[p] * 128 + lane * 2;
  float m0 = 0.f, m1 = 0.f;  // empty -> 0 per reference
  for (int k = 0; k < n; k += 8) {
    int kn = n - k;
    ushort2 v[8];
#pragma unroll
    for (int j = 0; j < 8; ++j)
      if (j < kn) v[j] = *reinterpret_cast<const ushort2*>(base + (size_t)(k + j) * 128);
#pragma unroll
    for (int j = 0; j < 8; ++j)
      if (j < kn) {
        m0 = fmaxf(m0, h2f(v[j].x));
        m1 = fmaxf(m1, h2f(v[j].y));
      }
  }
  if (MODE == 0) {
    ushort2 r;
    r.x = f2h(m0);
    r.y = f2h(m1);
    *reinterpret_cast<ushort2*>(aggh + (size_t)p * 128 + lane * 2) = r;
  } else {
    float2 r;
    r.x = m0;
    r.y = m1;
    *reinterpret_cast<float2*>(out + (size_t)p * 128 + lane * 2) = r;
    if (lane == 0) out[(size_t)P_POLY * 128 + p] = (float)p;
  }
}

// ---------------- k_Y: Y[p] = agg[p] @ W_bot + bias  (fp32 out) ----------------
__global__ __launch_bounds__(256) void k_Y(
    const unsigned short* __restrict__ aggh, const unsigned short* __restrict__ Wb,
    const float* __restrict__ bias, float* __restrict__ Yv)
{
  const int lane = threadIdx.x & 63;
  const int w = threadIdx.x >> 6;
  const int l15 = lane & 15;
  const int l4 = lane >> 4;
  const int koff = l4 * 8;
  const int c0 = w * 32 + l15;
  const int c1 = c0 + 16;

  short8 B0[4], B1[4];
#pragma unroll
  for (int kt = 0; kt < 4; ++kt) {
    B0[kt] = *reinterpret_cast<const short8*>(Wb + c0 * 128 + kt * 32 + koff);
    B1[kt] = *reinterpret_cast<const short8*>(Wb + c1 * 128 + kt * 32 + koff);
  }

  const int rowBase = blockIdx.x * 64;
  floatx4 accA[4], accB[4];
#pragma unroll
  for (int rg = 0; rg < 4; ++rg) {
    accA[rg] = (floatx4){0.f, 0.f, 0.f, 0.f};
    accB[rg] = (floatx4){0.f, 0.f, 0.f, 0.f};
  }
#pragma unroll
  for (int kt = 0; kt < 4; ++kt) {
#pragma unroll
    for (int rg = 0; rg < 4; ++rg) {
      int row = rowBase + rg * 16 + l15;
      row = row < P_POLY ? row : P_POLY - 1;
      short8 a = *reinterpret_cast<const short8*>(aggh + (size_t)row * 128 + kt * 32 + koff);
      accA[rg] = __builtin_amdgcn_mfma_f32_16x16x32_f16(a, B0[kt], accA[rg], 0, 0, 0);
      accB[rg] = __builtin_amdgcn_mfma_f32_16x16x32_f16(a, B1[kt], accB[rg], 0, 0, 0);
    }
  }
  const float bi0 = bias[c0], bi1 = bias[c1];
#pragma unroll
  for (int rg = 0; rg < 4; ++rg) {
#pragma unroll
    for (int r = 0; r < 4; ++r) {
      int row = rowBase + rg * 16 + l4 * 4 + r;
      if (row < P_POLY) {
        Yv[(size_t)row * 128 + c0] = accA[rg][r] + bi0;
        Yv[(size_t)row * 128 + c1] = accB[rg][r] + bi1;
      }
    }
  }
}

// ------------- K2/K3: z = h@W_top + Y[pid] ; LN; ReLU -> hp (in-place) -------------
__global__ __launch_bounds__(256) void k_enc(
    const unsigned short* __restrict__ hin,
    const float* __restrict__ Yv,      // [P][128] fp32 (includes bias)
    const int* __restrict__ pid,       // [N] sorted-row polyline id
    const unsigned short* __restrict__ Wt,  // [128 c][128 k] f16
    const float* __restrict__ gamma, const float* __restrict__ beta,
    unsigned short* __restrict__ hout)
{
  __shared__ float2 part[4][64];
  __shared__ float2 mufin[64];

  const int lane = threadIdx.x & 63;
  const int w = threadIdx.x >> 6;
  const int l15 = lane & 15;
  const int l4 = lane >> 4;
  const int koff = l4 * 8;
  const int c0 = w * 32 + l15;
  const int c1 = c0 + 16;
  const float ga0 = gamma[c0], ga1 = gamma[c1];
  const float bt0 = beta[c0], bt1 = beta[c1];

  short8 B0[4], B1[4];  // 32 VGPRs
#pragma unroll
  for (int kt = 0; kt < 4; ++kt) {
    B0[kt] = *reinterpret_cast<const short8*>(Wt + c0 * 128 + kt * 32 + koff);
    B1[kt] = *reinterpret_cast<const short8*>(Wt + c1 * 128 + kt * 32 + koff);
  }

  const int rowBase = blockIdx.x * 64;
  const unsigned short* ap0;
  const unsigned short* ap1;
  const unsigned short* ap2;
  const unsigned short* ap3;
  {
    int r0 = rowBase + 0 * 16 + l15; r0 = r0 < N_PTS ? r0 : N_PTS - 1;
    int r1 = rowBase + 1 * 16 + l15; r1 = r1 < N_PTS ? r1 : N_PTS - 1;
    int r2 = rowBase + 2 * 16 + l15; r2 = r2 < N_PTS ? r2 : N_PTS - 1;
    int r3 = rowBase + 3 * 16 + l15; r3 = r3 < N_PTS ? r3 : N_PTS - 1;
    ap0 = hin + (size_t)r0 * 128;
    ap1 = hin + (size_t)r1 * 128;
    ap2 = hin + (size_t)r2 * 128;
    ap3 = hin + (size_t)r3 * 128;
  }

  floatx4 accA0 = {0.f,0.f,0.f,0.f}, accB0 = {0.f,0.f,0.f,0.f};
  floatx4 accA1 = {0.f,0.f,0.f,0.f}, accB1 = {0.f,0.f,0.f,0.f};
  floatx4 accA2 = {0.f,0.f,0.f,0.f}, accB2 = {0.f,0.f,0.f,0.f};
  floatx4 accA3 = {0.f,0.f,0.f,0.f}, accB3 = {0.f,0.f,0.f,0.f};

#pragma unroll
  for (int kt = 0; kt < 4; ++kt) {
    short8 a0 = *reinterpret_cast<const short8*>(ap0 + kt * 32 + koff);
    short8 a1 = *reinterpret_cast<const short8*>(ap1 + kt * 32 + koff);
    short8 a2 = *reinterpret_cast<const short8*>(ap2 + kt * 32 + koff);
    short8 a3 = *reinterpret_cast<const short8*>(ap3 + kt * 32 + koff);
    accA0 = __builtin_amdgcn_mfma_f32_16x16x32_f16(a0, B0[kt], accA0, 0, 0, 0);
    accB0 = __builtin_amdgcn_mfma_f32_16x16x32_f16(a0, B1[kt], accB0, 0, 0, 0);
    accA1 = __builtin_amdgcn_mfma_f32_16x16x32_f16(a1, B0[kt], accA1, 0, 0, 0);
    accB1 = __builtin_amdgcn_mfma_f32_16x16x32_f16(a1, B1[kt], accB1, 0, 0, 0);
    accA2 = __builtin_amdgcn_mfma_f32_16x16x32_f16(a2, B0[kt], accA2, 0, 0, 0);
    accB2 = __builtin_amdgcn_mfma_f32_16x16x32_f16(a2, B1[kt], accB2, 0, 0, 0);
    accA3 = __builtin_amdgcn_mfma_f32_16x16x32_f16(a3, B0[kt], accA3, 0, 0, 0);
    accB3 = __builtin_amdgcn_mfma_f32_16x16x32_f16(a3, B1[kt], accB3, 0, 0, 0);
  }

  // Y add + LN partials
#pragma unroll
  for (int rg = 0; rg < 4; ++rg) {
    floatx4* aA = rg == 0 ? &accA0 : rg == 1 ? &accA1 : rg == 2 ? &accA2 : &accA3;
    floatx4* aB = rg == 0 ? &accB0 : rg == 1 ? &accB1 : rg == 2 ? &accB2 : &accB3;
    float s[4], ss[4];
#pragma unroll
    for (int r = 0; r < 4; ++r) {
      int row = rowBase + rg * 16 + l4 * 4 + r;
      row = row < N_PTS ? row : N_PTS - 1;
      int pv = pid[row];
      float z0 = (*aA)[r] + Yv[(size_t)pv * 128 + c0];
      float z1 = (*aB)[r] + Yv[(size_t)pv * 128 + c1];
      (*aA)[r] = z0;
      (*aB)[r] = z1;
      s[r] = z0 + z1;
      ss[r] = fmaf(z0, z0, z1 * z1);
    }
#pragma unroll
    for (int m = 1; m <= 8; m <<= 1) {
#pragma unroll
      for (int r = 0; r < 4; ++r) {
        s[r] += __shfl_xor(s[r], m);
        ss[r] += __shfl_xor(ss[r], m);
      }
    }
    if (l15 == 0) {
#pragma unroll
      for (int r = 0; r < 4; ++r)
        part[w][rg * 16 + l4 * 4 + r] = make_float2(s[r], ss[r]);
    }
  }
  __syncthreads();

  if (threadIdx.x < 64) {
    int rr = threadIdx.x;
    float2 qa = part[0][rr], qb = part[1][rr], qc = part[2][rr], qd = part[3][rr];
    float S = qa.x + qb.x + qc.x + qd.x;
    float SS = qa.y + qb.y + qc.y + qd.y;
    float mu = S * (1.f / 128.f);
    float rs = rsqrtf(SS * (1.f / 128.f) - mu * mu + EPSV);
    mufin[rr] = make_float2(mu, rs);
  }
  __syncthreads();

#pragma unroll
  for (int rg = 0; rg < 4; ++rg) {
    const floatx4* aA = rg == 0 ? &accA0 : rg == 1 ? &accA1 : rg == 2 ? &accA2 : &accA3;
    const floatx4* aB = rg == 0 ? &accB0 : rg == 1 ? &accB1 : rg == 2 ? &accB2 : &accB3;
#pragma unroll
    for (int r = 0; r < 4; ++r) {
      int rloc = rg * 16 + l4 * 4 + r;
      int row = rowBase + rloc;
      float2 q = mufin[rloc];
      float v0 = fmaxf(fmaf(((*aA)[r] - q.x) * q.y, ga0, bt0), 0.f);
      float v1 = fmaxf(fmaf(((*aB)[r] - q.x) * q.y, ga1, bt1), 0.f);
      if (row < N_PTS) {
        hout[(size_t)row * 128 + c0] = f2h(v0);
        hout[(size_t)row * 128 + c1] = f2h(v1);
      }
    }
  }
}

// ws layout (bytes)
#define WS_H      0            // 128,000,000  h sorted [N][128] f16
#define WS_AGG    128000000    // 12,800,000   agg [P][128] f16
#define WS_Y      140800000    // 25,600,000   Y [P][128] fp32
#define WS_CNT    166400000    // 200,000
#define WS_OFF    166604800    // 200,000
#define WS_BTOT   166809600    // 4,096
#define WS_PID    166813696    // 2,000,000
#define WS_IPOS   168813696    // 2,000,000
#define WS_LIST   170813696    // 12,800,000
#define WS_W      183613696    // 4 x 32,768
#define WS_NEED   183875840

__device__ __attribute__((aligned(256))) unsigned char g_fallback[WS_NEED];

extern "C" void kernel_launch(void* const* d_in, const int* in_sizes, int n_in,
                              void* d_out, int out_size, void* d_ws, size_t ws_size,
                              hipStream_t stream) {
  const float* x = (const float*)d_in[0];
  const int* ids = (const int*)d_in[1];
  const float* W0 = (const float*)d_in[2];
  const float* b0 = (const float*)d_in[3];
  const float* g0 = (const float*)d_in[4];
  const float* be0 = (const float*)d_in[5];
  const float* W1 = (const float*)d_in[6];
  const float* b1 = (const float*)d_in[7];
  const float* g1 = (const float*)d_in[8];
  const float* be1 = (const float*)d_in[9];
  const float* W2 = (const float*)d_in[10];
  const float* b2 = (const float*)d_in[11];
  const float* g2 = (const float*)d_in[12];
  const float* be2 = (const float*)d_in[13];

  char* ws = (char*)d_ws;
  if (ws_size < (size_t)WS_NEED) {
    void* p = nullptr;
    hipGetSymbolAddress(&p, HIP_SYMBOL(g_fallback));
    ws = (char*)p;
  }
  unsigned short* hp = (unsigned short*)(ws + WS_H);
  unsigned short* aggh = (unsigned short*)(ws + WS_AGG);
  float* Yv = (float*)(ws + WS_Y);
  unsigned int* cnt = (unsigned int*)(ws + WS_CNT);
  unsigned int* offsets = (unsigned int*)(ws + WS_OFF);
  unsigned int* btot = (unsigned int*)(ws + WS_BTOT);
  int* pid_perm = (int*)(ws + WS_PID);
  int* ipos = (int*)(ws + WS_IPOS);
  int* list = (int*)(ws + WS_LIST);
  unsigned short* Wt1 = (unsigned short*)(ws + WS_W);
  unsigned short* Wb1 = (unsigned short*)(ws + WS_W + 32768);
  unsigned short* Wt2 = (unsigned short*)(ws + WS_W + 65536);
  unsigned short* Wb2 = (unsigned short*)(ws + WS_W + 98304);
  float* out = (float*)d_out;

  hipMemsetAsync(cnt, 0, P_POLY * 4, stream);
  hipMemsetAsync(pid_perm, 0, N_PTS * 4, stream);
  hipMemsetAsync(ipos, 0, N_PTS * 4, stream);

  k_bucket<<<(N_PTS + 255) / 256, 256, 0, stream>>>(ids, cnt, list);
  k_scan1<<<196, 256, 0, stream>>>(cnt, btot);
  k_scan2<<<196, 256, 0, stream>>>(cnt, btot, list, offsets, pid_perm, ipos);
  k_wprep<<<256, 256, 0, stream>>>(W1, W2, Wt1, Wb1, Wt2, Wb2);
  k_enc0<<<4096, 256, 0, stream>>>(x, ipos, W0, b0, g0, be0, hp);
  k_segmax<0><<<P_POLY / 4, 256, 0, stream>>>(hp, cnt, offsets, aggh, nullptr);
  k_Y<<<(P_POLY + 63) / 64, 256, 0, stream>>>(aggh, Wb1, b1, Yv);
  k_enc<<<(N_PTS + 63) / 64, 256, 0, stream>>>(hp, Yv, pid_perm, Wt1, g1, be1, hp);
  k_segmax<0><<<P_POLY / 4, 256, 0, stream>>>(hp, cnt, offsets, aggh, nullptr);
  k_Y<<<(P_POLY + 63) / 64, 256, 0, stream>>>(aggh, Wb2, b2, Yv);
  k_enc<<<(N_PTS + 63) / 64, 256, 0, stream>>>(hp, Yv, pid_perm, Wt2, g2, be2, hp);
  k_segmax<1><<<P_POLY / 4, 256, 0, stream>>>(hp, cnt, offsets, nullptr, out);
}

// Round 7
// 497.951 us; speedup vs baseline: 1.2460x; 1.2007x over previous
//
#include <hip/hip_runtime.h>
#include <hip/hip_bf16.h>
#include <hip/hip_fp16.h>

#define N_PTS 500000
#define P_POLY 50000
#define IN_DIM 9
#define HDIM 128
#define EPSV 1e-5f
#define BCAP 64
#define NG 7813            // ceil(N_PTS / 64) offset-window groups
#define CAPR 96            // row capacity per group (64 + max polyline len)
#define HS 144             // LDS row stride in elems (288 B = 18*16, 16B-aligned)

typedef __attribute__((ext_vector_type(8))) short short8;
typedef __attribute__((ext_vector_type(4))) float floatx4;

__device__ __forceinline__ unsigned short f2h(float f) {
  return __half_as_ushort(__float2half(f));
}
__device__ __forceinline__ float h2f(unsigned short u) {
  return __half2float(__ushort_as_half(u));
}

// ---------------- bucket build ----------------
__global__ __launch_bounds__(256) void k_bucket(
    const int* __restrict__ ids, unsigned int* __restrict__ cnt, int* __restrict__ list)
{
  int i = blockIdx.x * blockDim.x + threadIdx.x;
  if (i < N_PTS) {
    int id = ids[i];
    unsigned k = atomicAdd(&cnt[id], 1u);
    list[id * BCAP + (k & (BCAP - 1))] = i;
  }
}

// ---------------- scan stage 1: per-block totals ----------------
__global__ __launch_bounds__(256) void k_scan1(
    const unsigned int* __restrict__ cnt, unsigned int* __restrict__ btot)
{
  __shared__ unsigned int s[256];
  int t = threadIdx.x;
  int i = blockIdx.x * 256 + t;
  s[t] = (i < P_POLY) ? cnt[i] : 0u;
  __syncthreads();
  for (int d = 128; d > 0; d >>= 1) {
    if (t < d) s[t] += s[t + d];
    __syncthreads();
  }
  if (t == 0) btot[blockIdx.x] = s[0];
}

// ---- scan stage 2: offsets + perm (sorted->orig) + group lists ----
__global__ __launch_bounds__(256) void k_scan2(
    const unsigned int* __restrict__ cnt, const unsigned int* __restrict__ btot,
    const int* __restrict__ list, unsigned int* __restrict__ offsets,
    int* __restrict__ perm, int* __restrict__ gcount, int* __restrict__ gplist)
{
  __shared__ unsigned int s[256];
  __shared__ unsigned int sbase;
  int b = blockIdx.x, t = threadIdx.x;
  int i = b * 256 + t;
  unsigned int v = (i < P_POLY) ? cnt[i] : 0u;
  s[t] = v;
  __syncthreads();
  for (int d = 1; d < 256; d <<= 1) {
    unsigned int tmp = (t >= d) ? s[t - d] : 0u;
    __syncthreads();
    s[t] += tmp;
    __syncthreads();
  }
  unsigned int incl = s[t];
  if (t == 0) {
    unsigned int base = 0;
    for (int j = 0; j < b; ++j) base += btot[j];
    sbase = base;
  }
  __syncthreads();
  unsigned int off = sbase + incl - v;  // exclusive prefix
  if (i < P_POLY) {
    offsets[i] = off;
    unsigned int n = v > BCAP ? (unsigned)BCAP : v;
    int g = (int)(off >> 6);
    int slot = atomicAdd(&gcount[g], 1);
    gplist[g * BCAP + (slot & (BCAP - 1))] = i;
    for (unsigned int k = 0; k < n; ++k)
      perm[off + k] = list[i * BCAP + k];
  }
}

// ---------------- W prep: split + transpose to f16 [col][128 k] ----------------
__global__ __launch_bounds__(256) void k_wprep(
    const float* __restrict__ W1, const float* __restrict__ W2,
    unsigned short* __restrict__ Wt1, unsigned short* __restrict__ Wb1,
    unsigned short* __restrict__ Wt2, unsigned short* __restrict__ Wb2)
{
  int idx = blockIdx.x * 256 + threadIdx.x;  // 256 blocks -> 65536
  int sel = idx >> 14;
  int e = idx & 16383;
  int c = e & 127;
  int k = e >> 7;
  const float* W = (sel < 2) ? W1 : W2;
  unsigned short* O = sel == 0 ? Wt1 : sel == 1 ? Wb1 : sel == 2 ? Wt2 : Wb2;
  int kg = k + ((sel & 1) ? 128 : 0);
  O[c * 128 + k] = f2h(W[kg * 128 + c]);
}

// ---------------- fused per-group network: MFMA layer helper ----------------
__device__ __forceinline__ void enc_layer(
    unsigned short* sh, const unsigned short* sagg, const int* pid_loc, char* smisc,
    const unsigned short* __restrict__ Wt, const unsigned short* __restrict__ Wb,
    const float* __restrict__ bias, const float* __restrict__ gamma,
    const float* __restrict__ beta, int w, int l15, int l4, int koff)
{
  const int c0 = w * 32 + l15;
  const int c1 = c0 + 16;
  floatx4 acc[6][2];
#pragma unroll
  for (int mt = 0; mt < 6; ++mt) {
    acc[mt][0] = (floatx4){0.f, 0.f, 0.f, 0.f};
    acc[mt][1] = (floatx4){0.f, 0.f, 0.f, 0.f};
  }
  int pl[6];
#pragma unroll
  for (int mt = 0; mt < 6; ++mt) pl[mt] = pid_loc[mt * 16 + l15];

#pragma unroll
  for (int kk = 0; kk < 4; ++kk) {
    short8 B0 = *reinterpret_cast<const short8*>(Wt + c0 * 128 + kk * 32 + koff);
    short8 B1 = *reinterpret_cast<const short8*>(Wt + c1 * 128 + kk * 32 + koff);
#pragma unroll
    for (int mt = 0; mt < 6; ++mt) {
      short8 a = *reinterpret_cast<const short8*>(sh + (mt * 16 + l15) * HS + kk * 32 + koff);
      acc[mt][0] = __builtin_amdgcn_mfma_f32_16x16x32_f16(a, B0, acc[mt][0], 0, 0, 0);
      acc[mt][1] = __builtin_amdgcn_mfma_f32_16x16x32_f16(a, B1, acc[mt][1], 0, 0, 0);
    }
  }
#pragma unroll
  for (int kk = 0; kk < 4; ++kk) {
    short8 B0 = *reinterpret_cast<const short8*>(Wb + c0 * 128 + kk * 32 + koff);
    short8 B1 = *reinterpret_cast<const short8*>(Wb + c1 * 128 + kk * 32 + koff);
#pragma unroll
    for (int mt = 0; mt < 6; ++mt) {
      short8 a = *reinterpret_cast<const short8*>(sagg + pl[mt] * HS + kk * 32 + koff);
      acc[mt][0] = __builtin_amdgcn_mfma_f32_16x16x32_f16(a, B0, acc[mt][0], 0, 0, 0);
      acc[mt][1] = __builtin_amdgcn_mfma_f32_16x16x32_f16(a, B1, acc[mt][1], 0, 0, 0);
    }
  }

  float bi0 = bias[c0], bi1 = bias[c1];
  float2* part = (float2*)smisc;            // [4][96]
  float2* mufin = (float2*)(smisc + 3072);  // [96]
#pragma unroll
  for (int mt = 0; mt < 6; ++mt) {
    float s[4], ss[4];
#pragma unroll
    for (int r = 0; r < 4; ++r) {
      float z0 = acc[mt][0][r] + bi0;
      float z1 = acc[mt][1][r] + bi1;
      acc[mt][0][r] = z0;
      acc[mt][1][r] = z1;
      s[r] = z0 + z1;
      ss[r] = fmaf(z0, z0, z1 * z1);
    }
#pragma unroll
    for (int m = 1; m <= 8; m <<= 1) {
#pragma unroll
      for (int r = 0; r < 4; ++r) {
        s[r] += __shfl_xor(s[r], m);
        ss[r] += __shfl_xor(ss[r], m);
      }
    }
    if (l15 == 0) {
#pragma unroll
      for (int r = 0; r < 4; ++r)
        part[w * CAPR + mt * 16 + l4 * 4 + r] = make_float2(s[r], ss[r]);
    }
  }
  __syncthreads();   // all MFMA reads of sh/sagg complete before this point
  if (threadIdx.x < CAPR) {
    int rr = threadIdx.x;
    float2 qa = part[0 * CAPR + rr], qb = part[1 * CAPR + rr];
    float2 qc = part[2 * CAPR + rr], qd = part[3 * CAPR + rr];
    float S = qa.x + qb.x + qc.x + qd.x;
    float SS = qa.y + qb.y + qc.y + qd.y;
    float mu = S * (1.f / 128.f);
    float rv = rsqrtf(SS * (1.f / 128.f) - mu * mu + EPSV);
    mufin[rr] = make_float2(mu, rv);
  }
  __syncthreads();
  float ga0 = gamma[c0], ga1 = gamma[c1], bt0 = beta[c0], bt1 = beta[c1];
#pragma unroll
  for (int mt = 0; mt < 6; ++mt) {
#pragma unroll
    for (int r = 0; r < 4; ++r) {
      int row = mt * 16 + l4 * 4 + r;
      float2 q = mufin[row];
      float v0 = fmaxf(fmaf((acc[mt][0][r] - q.x) * q.y, ga0, bt0), 0.f);
      float v1 = fmaxf(fmaf((acc[mt][1][r] - q.x) * q.y, ga1, bt1), 0.f);
      sh[row * HS + c0] = f2h(v0);
      sh[row * HS + c1] = f2h(v1);
    }
  }
  __syncthreads();
}

// ---------------- fused kernel ----------------
__global__ __launch_bounds__(256, 3) void k_fused(
    const float* __restrict__ x, const int* __restrict__ perm,
    const unsigned int* __restrict__ cnt, const unsigned int* __restrict__ offsets,
    const int* __restrict__ gcount, const int* __restrict__ gplist,
    const float* __restrict__ W0, const float* __restrict__ b0,
    const float* __restrict__ g0, const float* __restrict__ be0,
    const unsigned short* __restrict__ Wt1, const unsigned short* __restrict__ Wb1,
    const float* __restrict__ b1, const float* __restrict__ g1, const float* __restrict__ be1,
    const unsigned short* __restrict__ Wt2, const unsigned short* __restrict__ Wb2,
    const float* __restrict__ b2, const float* __restrict__ g2, const float* __restrict__ be2,
    float* __restrict__ out)
{
  __shared__ unsigned short sh[CAPR * HS];    // 27648 B : h tile
  __shared__ unsigned short sagg[BCAP * HS];  // 18432 B : per-slot agg
  __shared__ char smisc[3840];                // xs (enc0) / part+mufin (layers)
  __shared__ short sl_off[BCAP], sl_n[BCAP];
  __shared__ int sl_p[BCAP];
  __shared__ int pid_loc[CAPR];
  __shared__ int s_rs, s_nrows;

  const int g = blockIdx.x;
  const int npoly0 = gcount[g];
  if (npoly0 <= 0) return;  // uniform exit before any barrier
  const int npoly = npoly0 > BCAP ? BCAP : npoly0;
  const int tid = threadIdx.x;
  const int lane = tid & 63;
  const int w = tid >> 6;
  const int l15 = lane & 15;
  const int l4 = lane >> 4;
  const int koff = l4 * 8;

  // ---- meta: row range + slot tables (wave 0) ----
  if (tid < 64) {
    int s = tid;
    int off = 0x7FFFFFFF, n = 0, end = 0, p = 0;
    if (s < npoly) {
      p = gplist[g * BCAP + s];
      off = (int)offsets[p];
      n = (int)cnt[p];
      if (n > BCAP) n = BCAP;
      end = off + n;
    }
    int rsv = off, rev = end;
#pragma unroll
    for (int m = 32; m >= 1; m >>= 1) {
      rsv = min(rsv, __shfl_xor(rsv, m));
      rev = max(rev, __shfl_xor(rev, m));
    }
    if (s == 0) { s_rs = rsv; s_nrows = min(rev - rsv, CAPR); }
    if (s < npoly) {
      int ls = off - rsv;
      sl_off[s] = (short)ls;
      sl_n[s] = (short)n;
      sl_p[s] = p;
      for (int k = 0; k < n; ++k)
        if (ls + k < CAPR) pid_loc[ls + k] = s;
    }
    int nr = min(rev - rsv, CAPR);
    for (int r = nr + s; r < CAPR; r += 64) pid_loc[r] = 0;
  }
  __syncthreads();
  const int rs = s_rs;
  const int nrows = s_nrows;

  // ---- gather x rows into LDS ----
  float* xs = (float*)smisc;  // [96][9]
  for (int e = tid; e < nrows * IN_DIM; e += 256) {
    int r = e / IN_DIM;
    int k = e - r * IN_DIM;
    unsigned o = (unsigned)perm[rs + r];
    if (o >= N_PTS) o = 0;  // safety clamp
    xs[e] = x[(size_t)o * IN_DIM + k];
  }
  __syncthreads();

  // ---- enc0: row-per-wave VALU matvec + LN + ReLU -> sh ----
  {
    float w0a[9], w0b[9];
#pragma unroll
    for (int k = 0; k < 9; ++k) {
      float2 t = *reinterpret_cast<const float2*>(W0 + k * 128 + 2 * lane);
      w0a[k] = t.x;
      w0b[k] = t.y;
    }
    float2 bb = *reinterpret_cast<const float2*>(b0 + 2 * lane);
    float2 gg = *reinterpret_cast<const float2*>(g0 + 2 * lane);
    float2 ee = *reinterpret_cast<const float2*>(be0 + 2 * lane);
    for (int r = w; r < nrows; r += 4) {
      float z0 = bb.x, z1 = bb.y;
#pragma unroll
      for (int k = 0; k < 9; ++k) {
        float xv = xs[r * 9 + k];
        z0 = fmaf(xv, w0a[k], z0);
        z1 = fmaf(xv, w0b[k], z1);
      }
      float s = z0 + z1, ss = fmaf(z0, z0, z1 * z1);
#pragma unroll
      for (int m = 32; m >= 1; m >>= 1) {
        s += __shfl_xor(s, m);
        ss += __shfl_xor(ss, m);
      }
      float mu = s * (1.f / 128.f);
      float rv = rsqrtf(ss * (1.f / 128.f) - mu * mu + EPSV);
      float v0 = fmaxf(fmaf((z0 - mu) * rv, gg.x, ee.x), 0.f);
      float v1 = fmaxf(fmaf((z1 - mu) * rv, gg.y, ee.y), 0.f);
      *reinterpret_cast<ushort2*>(sh + r * HS + 2 * lane) = make_ushort2(f2h(v0), f2h(v1));
    }
  }
  __syncthreads();  // h ready; xs dead

  // ---- segmax0 (LDS->LDS) ----
  for (int s = w; s < npoly; s += 4) {
    int ls = sl_off[s], n = sl_n[s];
    float m0 = 0.f, m1 = 0.f;
    for (int k = 0; k < n; ++k) {
      ushort2 v = *reinterpret_cast<const ushort2*>(sh + (ls + k) * HS + 2 * lane);
      m0 = fmaxf(m0, h2f(v.x));
      m1 = fmaxf(m1, h2f(v.y));
    }
    *reinterpret_cast<ushort2*>(sagg + s * HS + 2 * lane) = make_ushort2(f2h(m0), f2h(m1));
  }
  __syncthreads();

  enc_layer(sh, sagg, pid_loc, smisc, Wt1, Wb1, b1, g1, be1, w, l15, l4, koff);

  // ---- segmax1 ----
  for (int s = w; s < npoly; s += 4) {
    int ls = sl_off[s], n = sl_n[s];
    float m0 = 0.f, m1 = 0.f;
    for (int k = 0; k < n; ++k) {
      ushort2 v = *reinterpret_cast<const ushort2*>(sh + (ls + k) * HS + 2 * lane);
      m0 = fmaxf(m0, h2f(v.x));
      m1 = fmaxf(m1, h2f(v.y));
    }
    *reinterpret_cast<ushort2*>(sagg + s * HS + 2 * lane) = make_ushort2(f2h(m0), f2h(m1));
  }
  __syncthreads();

  enc_layer(sh, sagg, pid_loc, smisc, Wt2, Wb2, b2, g2, be2, w, l15, l4, koff);

  // ---- segmax2: final -> global out (fp32) + arange tail ----
  for (int s = w; s < npoly; s += 4) {
    int ls = sl_off[s], n = sl_n[s];
    float m0 = 0.f, m1 = 0.f;
    for (int k = 0; k < n; ++k) {
      ushort2 v = *reinterpret_cast<const ushort2*>(sh + (ls + k) * HS + 2 * lane);
      m0 = fmaxf(m0, h2f(v.x));
      m1 = fmaxf(m1, h2f(v.y));
    }
    int p = sl_p[s];
    *reinterpret_cast<float2*>(out + (size_t)p * 128 + 2 * lane) = make_float2(m0, m1);
    if (lane == 0) out[(size_t)P_POLY * 128 + p] = (float)p;
  }
}

// ws layout (bytes)
#define WS_CNT   0           // 204800
#define WS_OFF   204800      // 204800
#define WS_BTOT  409600      // 4096
#define WS_PERM  413696      // 2000000
#define WS_LIST  2413696     // 12800000
#define WS_GCNT  15213696    // 32768
#define WS_GPL   15246464    // 2000896
#define WS_W     17247360    // 131072
#define WS_NEED  17378432

__device__ __attribute__((aligned(256))) unsigned char g_fallback[WS_NEED];

extern "C" void kernel_launch(void* const* d_in, const int* in_sizes, int n_in,
                              void* d_out, int out_size, void* d_ws, size_t ws_size,
                              hipStream_t stream) {
  const float* x = (const float*)d_in[0];
  const int* ids = (const int*)d_in[1];
  const float* W0 = (const float*)d_in[2];
  const float* b0 = (const float*)d_in[3];
  const float* g0 = (const float*)d_in[4];
  const float* be0 = (const float*)d_in[5];
  const float* W1 = (const float*)d_in[6];
  const float* b1 = (const float*)d_in[7];
  const float* g1 = (const float*)d_in[8];
  const float* be1 = (const float*)d_in[9];
  const float* W2 = (const float*)d_in[10];
  const float* b2 = (const float*)d_in[11];
  const float* g2 = (const float*)d_in[12];
  const float* be2 = (const float*)d_in[13];

  char* ws = (char*)d_ws;
  if (ws_size < (size_t)WS_NEED) {
    void* p = nullptr;
    hipGetSymbolAddress(&p, HIP_SYMBOL(g_fallback));
    ws = (char*)p;
  }
  unsigned int* cnt = (unsigned int*)(ws + WS_CNT);
  unsigned int* offsets = (unsigned int*)(ws + WS_OFF);
  unsigned int* btot = (unsigned int*)(ws + WS_BTOT);
  int* perm = (int*)(ws + WS_PERM);
  int* list = (int*)(ws + WS_LIST);
  int* gcount = (int*)(ws + WS_GCNT);
  int* gplist = (int*)(ws + WS_GPL);
  unsigned short* Wt1 = (unsigned short*)(ws + WS_W);
  unsigned short* Wb1 = (unsigned short*)(ws + WS_W + 32768);
  unsigned short* Wt2 = (unsigned short*)(ws + WS_W + 65536);
  unsigned short* Wb2 = (unsigned short*)(ws + WS_W + 98304);
  float* out = (float*)d_out;

  hipMemsetAsync(cnt, 0, P_POLY * 4, stream);
  hipMemsetAsync(gcount, 0, 32768, stream);

  k_bucket<<<(N_PTS + 255) / 256, 256, 0, stream>>>(ids, cnt, list);
  k_scan1<<<196, 256, 0, stream>>>(cnt, btot);
  k_scan2<<<196, 256, 0, stream>>>(cnt, btot, list, offsets, perm, gcount, gplist);
  k_wprep<<<256, 256, 0, stream>>>(W1, W2, Wt1, Wb1, Wt2, Wb2);
  k_fused<<<NG, 256, 0, stream>>>(x, perm, cnt, offsets, gcount, gplist,
                                  W0, b0, g0, be0,
                                  Wt1, Wb1, b1, g1, be1,
                                  Wt2, Wb2, b2, g2, be2, out);
}